// Round 1
// baseline (121.969 us; speedup 1.0000x reference)
//
#include <hip/hip_runtime.h>

#define NN 8192
#define BB 32
#define EMB 16
#define HID 64
#define MS 16           // m-range splits

typedef __attribute__((ext_vector_type(8))) short bf16x8;
typedef __attribute__((ext_vector_type(4))) float f32x4;

static __device__ inline unsigned short f2b(float f) {   // round-to-nearest-even
    union { float f; unsigned u; } v; v.f = f;
    return (unsigned short)((v.u + 0x7fffu + ((v.u >> 16) & 1u)) >> 16);
}

// pack two fp32 (truncate) into one dword of bf16: [hi16(odd) : hi16(even)]
static __device__ inline unsigned packbf(unsigned e_even, unsigned e_odd) {
#if __has_builtin(__builtin_amdgcn_perm)
    return __builtin_amdgcn_perm(e_odd, e_even, 0x07060302u);
#else
    return (e_odd & 0xFFFF0000u) | (e_even >> 16);
#endif
}

// ---------------------------------------------------------------------------
// K1: fused operand prep (all stored in MFMA-fragment lane order).
//  bx [0,256):    VTf[c][u][lane]  : V fragments (PV A-operand)
//  bx [256,384):  Afrag[c][h][lane]: adj m-rows (score A-operand, permuted)
//  bx [384,512):  adjS[n][d] = bf16(adj*log2e)  (score B side, row-major)
//  bx [512,1024): WbufB[n][c*64+o] bf16 node-adaptive weights {x0,x1,y0,y1,b}
// ---------------------------------------------------------------------------
__global__ void k_build(const float* __restrict__ x, const float* __restrict__ adj,
                        const float* __restrict__ wp, const float* __restrict__ bp,
                        short* __restrict__ VTf, short* __restrict__ Afrag,
                        short* __restrict__ adjS, unsigned short* __restrict__ WbufB) {
    const int t = threadIdx.x;
    const int bx = blockIdx.x;
    if (bx < 256) {
        const int c = bx;
        const int u = t >> 6, lane = t & 63, l = lane & 15, q = lane >> 4;
        const int j = 16 * u + l, b = j >> 1, ch = j & 1;
        const int m0 = 32 * c + 8 * q;
        const float* xp = x + (size_t)b * (NN * 2) + m0 * 2;
        uint4 d;
        unsigned dd[4];
#pragma unroll
        for (int i = 0; i < 4; ++i) {
            float4 xx = *(const float4*)(xp + 4 * i);
            float v0 = ch ? xx.y : xx.x;
            float v1 = ch ? xx.w : xx.z;
            dd[i] = (unsigned)f2b(v0) | ((unsigned)f2b(v1) << 16);
        }
        d.x = dd[0]; d.y = dd[1]; d.z = dd[2]; d.w = dd[3];
        *(uint4*)(VTf + ((size_t)(c * 4 + u) * 64 + lane) * 8) = d;
    } else if (bx < 384) {
        const int cc = t >> 7, tt = t & 127;
        const int c = (bx - 256) * 2 + cc;
        const int h = tt >> 6, lane = tt & 63, l = lane & 15, q = lane >> 4;
        const int row = 32 * c + 8 * (l >> 2) + (l & 3) + 4 * h;
        const float* ap = adj + (size_t)row * EMB + (q & 1) * 8;
        float4 a0 = *(const float4*)(ap);
        float4 a1 = *(const float4*)(ap + 4);
        uint4 d;
        d.x = (unsigned)f2b(a0.x) | ((unsigned)f2b(a0.y) << 16);
        d.y = (unsigned)f2b(a0.z) | ((unsigned)f2b(a0.w) << 16);
        d.z = (unsigned)f2b(a1.x) | ((unsigned)f2b(a1.y) << 16);
        d.w = (unsigned)f2b(a1.z) | ((unsigned)f2b(a1.w) << 16);
        *(uint4*)(Afrag + ((size_t)(c * 2 + h) * 64 + lane) * 8) = d;
    } else if (bx < 512) {
        const float L2E = 1.4426950408889634f;
        int idx = (bx - 384) * 256 + t;
        float4 aa = *(const float4*)(adj + (size_t)idx * 4);
        uint2 us;
        us.x = (unsigned)f2b(aa.x * L2E) | ((unsigned)f2b(aa.y * L2E) << 16);
        us.y = (unsigned)f2b(aa.z * L2E) | ((unsigned)f2b(aa.w * L2E) << 16);
        *(uint2*)(adjS + (size_t)idx * 4) = us;
    } else {
        const int nl = t >> 4, og = t & 15;
        const int n = (bx - 512) * 16 + nl;
        const float4* wp4 = (const float4*)wp;
        const float4* bp4 = (const float4*)bp;
        float an[EMB];
#pragma unroll
        for (int d = 0; d < EMB; ++d) an[d] = adj[n * EMB + d];
        float4 w[5];
#pragma unroll
        for (int c = 0; c < 5; ++c) { w[c].x = w[c].y = w[c].z = w[c].w = 0.f; }
#pragma unroll
        for (int d = 0; d < EMB; ++d) {
            float a = an[d];
#pragma unroll
            for (int c = 0; c < 4; ++c) {
                float4 p = wp4[(d * 4 + c) * 16 + og];
                w[c].x += a * p.x; w[c].y += a * p.y; w[c].z += a * p.z; w[c].w += a * p.w;
            }
            float4 pb = bp4[d * 16 + og];
            w[4].x += a * pb.x; w[4].y += a * pb.y; w[4].z += a * pb.z; w[4].w += a * pb.w;
        }
#pragma unroll
        for (int c = 0; c < 5; ++c) {
            ushort4 pk;
            pk.x = f2b(w[c].x); pk.y = f2b(w[c].y); pk.z = f2b(w[c].z); pk.w = f2b(w[c].w);
            *(ushort4*)(WbufB + (size_t)n * 320 + c * 64 + og * 4) = pk;
        }
    }
}

// ---------------------------------------------------------------------------
// K2: MFMA flash propagation with explicit 1-deep ping-pong prefetch.
// 4 waves/block, 32 n per wave, barrier/LDS/atomic-free. bf16 partials out.
// ---------------------------------------------------------------------------
__launch_bounds__(256, 3)
__global__ void k_prop(const short* __restrict__ Afrag, const short* __restrict__ adjS,
                       const short* __restrict__ VTf,
                       short* __restrict__ ynum, float* __restrict__ den) {
    const int t = threadIdx.x;
    const int wv = t >> 6;
    const int lane = t & 63;
    const int l = lane & 15;
    const int q = lane >> 4;
    const int n0 = blockIdx.x * 128 + wv * 32;
    const int cbeg = blockIdx.y * (NN / MS / 32);   // 16 c-subtiles per block
    const int cend = cbeg + (NN / MS / 32);

    // loop-invariant score B-fragments (log2e-scaled), k>=16 zeroed
    bf16x8 Bn[2];
    bf16x8 zv = {0, 0, 0, 0, 0, 0, 0, 0};
#pragma unroll
    for (int s = 0; s < 2; ++s) {
        const short* src = adjS + (size_t)(n0 + 16 * s + l) * EMB + (q & 1) * 8;
        bf16x8 v = *(const bf16x8*)src;
        Bn[s] = (q < 2) ? v : zv;
    }
    const short one = (short)0x3F80;
    bf16x8 ones = {one, one, one, one, one, one, one, one};

    f32x4 acc[4][2];
    f32x4 dacc[2];
#pragma unroll
    for (int u = 0; u < 4; ++u)
#pragma unroll
        for (int s = 0; s < 2; ++s) { acc[u][s][0] = acc[u][s][1] = acc[u][s][2] = acc[u][s][3] = 0.f; }
#pragma unroll
    for (int s = 0; s < 2; ++s) { dacc[s][0] = dacc[s][1] = dacc[s][2] = dacc[s][3] = 0.f; }

    const short* Ap = Afrag + (size_t)lane * 8;   // + cg*1024 + h*512
    const short* Vp = VTf + (size_t)lane * 8;     // + cg*2048 + u*512

#define LOADF(cg, a0, a1, vv)                                            \
    do {                                                                 \
        a0 = *(const bf16x8*)(Ap + (size_t)(cg) * 1024);                 \
        a1 = *(const bf16x8*)(Ap + (size_t)(cg) * 1024 + 512);           \
        vv[0] = *(const bf16x8*)(Vp + (size_t)(cg) * 2048);              \
        vv[1] = *(const bf16x8*)(Vp + (size_t)(cg) * 2048 + 512);        \
        vv[2] = *(const bf16x8*)(Vp + (size_t)(cg) * 2048 + 1024);       \
        vv[3] = *(const bf16x8*)(Vp + (size_t)(cg) * 2048 + 1536);       \
    } while (0)

    auto compute = [&](bf16x8 Af0, bf16x8 Af1, bf16x8* Vf) {
        f32x4 z = {0.f, 0.f, 0.f, 0.f};
        f32x4 S0[2], S1[2];
#pragma unroll
        for (int s = 0; s < 2; ++s) {
            S0[s] = __builtin_amdgcn_mfma_f32_16x16x32_bf16(Af0, Bn[s], z, 0, 0, 0);
            S1[s] = __builtin_amdgcn_mfma_f32_16x16x32_bf16(Af1, Bn[s], z, 0, 0, 0);
        }
#pragma unroll
        for (int s = 0; s < 2; ++s) {
            unsigned w0[4], w1[4];
#pragma unroll
            for (int r = 0; r < 4; ++r) {
                union { float f; unsigned u; } p0, p1;
                p0.f = __builtin_amdgcn_exp2f(fmaxf(S0[s][r], 0.f));
                p1.f = __builtin_amdgcn_exp2f(fmaxf(S1[s][r], 0.f));
                w0[r] = p0.u;      // j = r      (h=0)
                w1[r] = p1.u;      // j = 4 + r  (h=1)
            }
            union { bf16x8 v; unsigned d[4]; } pf;
            pf.d[0] = packbf(w0[0], w0[1]);
            pf.d[1] = packbf(w0[2], w0[3]);
            pf.d[2] = packbf(w1[0], w1[1]);
            pf.d[3] = packbf(w1[2], w1[3]);
#pragma unroll
            for (int u = 0; u < 4; ++u)
                acc[u][s] = __builtin_amdgcn_mfma_f32_16x16x32_bf16(Vf[u], pf.v, acc[u][s], 0, 0, 0);
            dacc[s] = __builtin_amdgcn_mfma_f32_16x16x32_bf16(ones, pf.v, dacc[s], 0, 0, 0);
        }
    };

    bf16x8 a0A, a1A, vA[4], a0B, a1B, vB[4];
    LOADF(cbeg, a0A, a1A, vA);
    for (int cg = cbeg; cg < cend; cg += 2) {
        LOADF(cg + 1, a0B, a1B, vB);          // prefetch odd tile
        compute(a0A, a1A, vA);                // compute even tile (loads long done)
        int cg2 = (cg + 2 < cend) ? cg + 2 : cbeg;   // clamped redundant last load
        LOADF(cg2, a0A, a1A, vA);             // prefetch next even tile
        compute(a0B, a1B, vB);                // compute odd tile
    }
#undef LOADF

    // stores: bf16 partials [split][n][64]; den rows all equal -> dacc[s][0]
    short* yp = ynum + (size_t)blockIdx.y * NN * HID;
#pragma unroll
    for (int s = 0; s < 2; ++s) {
        const int n = n0 + 16 * s + l;
#pragma unroll
        for (int u = 0; u < 4; ++u) {
            union { float f; unsigned u; } a0, a1, a2, a3;
            a0.f = acc[u][s][0]; a1.f = acc[u][s][1]; a2.f = acc[u][s][2]; a3.f = acc[u][s][3];
            uint2 pk;
            pk.x = packbf(a0.u, a1.u);
            pk.y = packbf(a2.u, a3.u);
            *(uint2*)(yp + (size_t)n * HID + 16 * u + 4 * q) = pk;
        }
        if (q == 0) den[(size_t)blockIdx.y * NN + n] = dacc[s][0];
    }
}

// ---------------------------------------------------------------------------
// K3: epilogue. 16 nodes/block; reduce MS bf16 partials, normalize, apply
// bf16 per-node weights, nontemporal write out [32][8192][64] fp32.
// ---------------------------------------------------------------------------
__global__ void k_epi(const unsigned short* __restrict__ WbufB, const float* __restrict__ x,
                      const short* __restrict__ ynum, const float* __restrict__ den,
                      float* __restrict__ out) {
    const int nl = threadIdx.x >> 4, og = threadIdx.x & 15;
    const int n = blockIdx.x * 16 + nl;
    __shared__ float xl[16][68];
    __shared__ float yl[16][68];

    float4 W[5];
#pragma unroll
    for (int c = 0; c < 5; ++c) {
        ushort4 pw = *(const ushort4*)(WbufB + (size_t)n * 320 + c * 64 + og * 4);
        union { unsigned u; float f; } c0, c1, c2, c3;
        c0.u = (unsigned)pw.x << 16; c1.u = (unsigned)pw.y << 16;
        c2.u = (unsigned)pw.z << 16; c3.u = (unsigned)pw.w << 16;
        W[c].x = c0.f; W[c].y = c1.f; W[c].z = c2.f; W[c].w = c3.f;
    }

    float4 ysum; ysum.x = ysum.y = ysum.z = ysum.w = 0.f;
    float dsum = 0.f;
#pragma unroll
    for (int s = 0; s < MS; ++s) {
        ushort4 p = *(const ushort4*)(ynum + ((size_t)s * NN + n) * HID + og * 4);
        union { unsigned u; float f; } c0, c1, c2, c3;
        c0.u = (unsigned)p.x << 16; c1.u = (unsigned)p.y << 16;
        c2.u = (unsigned)p.z << 16; c3.u = (unsigned)p.w << 16;
        ysum.x += c0.f; ysum.y += c1.f; ysum.z += c2.f; ysum.w += c3.f;
        dsum += den[(size_t)s * NN + n];
    }
    float rden = 1.f / dsum;
    *(float4*)&yl[nl][og * 4] = make_float4(ysum.x * rden, ysum.y * rden, ysum.z * rden, ysum.w * rden);

    float2 x0 = *(const float2*)(x + ((size_t)(og * 2) * NN + n) * 2);
    float2 x1 = *(const float2*)(x + ((size_t)(og * 2 + 1) * NN + n) * 2);
    xl[nl][og * 4 + 0] = x0.x; xl[nl][og * 4 + 1] = x0.y;
    xl[nl][og * 4 + 2] = x1.x; xl[nl][og * 4 + 3] = x1.y;
    __syncthreads();

#pragma unroll 4
    for (int b = 0; b < BB; ++b) {
        float xb0 = xl[nl][2 * b], xb1 = xl[nl][2 * b + 1];
        float yb0 = yl[nl][2 * b], yb1 = yl[nl][2 * b + 1];
        f32x4 o4;
        o4[0] = xb0 * W[0].x + xb1 * W[1].x + yb0 * W[2].x + yb1 * W[3].x + W[4].x;
        o4[1] = xb0 * W[0].y + xb1 * W[1].y + yb0 * W[2].y + yb1 * W[3].y + W[4].y;
        o4[2] = xb0 * W[0].z + xb1 * W[1].z + yb0 * W[2].z + yb1 * W[3].z + W[4].z;
        o4[3] = xb0 * W[0].w + xb1 * W[1].w + yb0 * W[2].w + yb1 * W[3].w + W[4].w;
        __builtin_nontemporal_store(o4, (f32x4*)(out + ((size_t)b * NN + n) * HID + og * 4));
    }
}

// ---------------------------------------------------------------------------
extern "C" void kernel_launch(void* const* d_in, const int* in_sizes, int n_in,
                              void* d_out, int out_size, void* d_ws, size_t ws_size,
                              hipStream_t stream) {
    const float* x   = (const float*)d_in[0];   // [32, 8192, 2]
    const float* adj = (const float*)d_in[1];   // [8192, 16]
    const float* wp  = (const float*)d_in[2];   // [16, 2, 2, 64]
    const float* bp  = (const float*)d_in[3];   // [16, 64]
    float* out = (float*)d_out;                 // [32, 8192, 64]

    char* w = (char*)d_ws;
    short* VTf   = (short*)w;                                   // 1 MB
    short* Afrag = VTf + (size_t)256 * 4 * 64 * 8;              // 512 KB
    short* adjS  = Afrag + (size_t)256 * 2 * 64 * 8;            // 256 KB
    unsigned short* WbufB = (unsigned short*)(adjS + (size_t)NN * EMB);  // 5.25 MB
    short* ynum  = (short*)(WbufB + (size_t)NN * 320);          // 16 MB
    float* den   = (float*)(ynum + (size_t)MS * NN * HID);      // 512 KB

    k_build<<<1024, 256, 0, stream>>>(x, adj, wp, bp, VTf, Afrag, adjS, WbufB);
    k_prop<<<dim3(NN / 128, MS), 256, 0, stream>>>(Afrag, adjS, VTf, ynum, den);
    k_epi<<<NN / 16, 256, 0, stream>>>(WbufB, x, ynum, den, out);
}

// Round 2
// 121.358 us; speedup vs baseline: 1.0050x; 1.0050x over previous
//
#include <hip/hip_runtime.h>

#define NN 8192
#define BB 32
#define EMB 16
#define HID 64
#define MS 16           // m-range splits

typedef __attribute__((ext_vector_type(8))) short bf16x8;
typedef __attribute__((ext_vector_type(4))) float f32x4;

static __device__ inline unsigned short f2b(float f) {   // round-to-nearest-even
    union { float f; unsigned u; } v; v.f = f;
    return (unsigned short)((v.u + 0x7fffu + ((v.u >> 16) & 1u)) >> 16);
}

// pack two fp32 (truncate) into one dword of bf16: [hi16(odd) : hi16(even)]
static __device__ inline unsigned packbf(unsigned e_even, unsigned e_odd) {
#if __has_builtin(__builtin_amdgcn_perm)
    return __builtin_amdgcn_perm(e_odd, e_even, 0x07060302u);
#else
    return (e_odd & 0xFFFF0000u) | (e_even >> 16);
#endif
}

// ---------------------------------------------------------------------------
// K1: fused operand prep (all stored in MFMA-fragment lane order).
//  bx [0,256):    VTf[c][u][lane]  : V fragments (PV A-operand)
//  bx [256,384):  Afrag[c][h][lane]: adj m-rows (score A-operand, permuted)
//  bx [384,512):  adjS[n][d] = bf16(adj*log2e)  (score B side, row-major)
//  bx [512,1024): WbufB[n][c*64+o] bf16 node-adaptive weights {x0,x1,y0,y1,b}
// ---------------------------------------------------------------------------
__global__ void k_build(const float* __restrict__ x, const float* __restrict__ adj,
                        const float* __restrict__ wp, const float* __restrict__ bp,
                        short* __restrict__ VTf, short* __restrict__ Afrag,
                        short* __restrict__ adjS, unsigned short* __restrict__ WbufB) {
    const int t = threadIdx.x;
    const int bx = blockIdx.x;
    if (bx < 256) {
        const int c = bx;
        const int u = t >> 6, lane = t & 63, l = lane & 15, q = lane >> 4;
        const int j = 16 * u + l, b = j >> 1, ch = j & 1;
        const int m0 = 32 * c + 8 * q;
        const float* xp = x + (size_t)b * (NN * 2) + m0 * 2;
        uint4 d;
        unsigned dd[4];
#pragma unroll
        for (int i = 0; i < 4; ++i) {
            float4 xx = *(const float4*)(xp + 4 * i);
            float v0 = ch ? xx.y : xx.x;
            float v1 = ch ? xx.w : xx.z;
            dd[i] = (unsigned)f2b(v0) | ((unsigned)f2b(v1) << 16);
        }
        d.x = dd[0]; d.y = dd[1]; d.z = dd[2]; d.w = dd[3];
        *(uint4*)(VTf + ((size_t)(c * 4 + u) * 64 + lane) * 8) = d;
    } else if (bx < 384) {
        const int cc = t >> 7, tt = t & 127;
        const int c = (bx - 256) * 2 + cc;
        const int h = tt >> 6, lane = tt & 63, l = lane & 15, q = lane >> 4;
        const int row = 32 * c + 8 * (l >> 2) + (l & 3) + 4 * h;
        const float* ap = adj + (size_t)row * EMB + (q & 1) * 8;
        float4 a0 = *(const float4*)(ap);
        float4 a1 = *(const float4*)(ap + 4);
        uint4 d;
        d.x = (unsigned)f2b(a0.x) | ((unsigned)f2b(a0.y) << 16);
        d.y = (unsigned)f2b(a0.z) | ((unsigned)f2b(a0.w) << 16);
        d.z = (unsigned)f2b(a1.x) | ((unsigned)f2b(a1.y) << 16);
        d.w = (unsigned)f2b(a1.z) | ((unsigned)f2b(a1.w) << 16);
        *(uint4*)(Afrag + ((size_t)(c * 2 + h) * 64 + lane) * 8) = d;
    } else if (bx < 512) {
        const float L2E = 1.4426950408889634f;
        int idx = (bx - 384) * 256 + t;
        float4 aa = *(const float4*)(adj + (size_t)idx * 4);
        uint2 us;
        us.x = (unsigned)f2b(aa.x * L2E) | ((unsigned)f2b(aa.y * L2E) << 16);
        us.y = (unsigned)f2b(aa.z * L2E) | ((unsigned)f2b(aa.w * L2E) << 16);
        *(uint2*)(adjS + (size_t)idx * 4) = us;
    } else {
        const int nl = t >> 4, og = t & 15;
        const int n = (bx - 512) * 16 + nl;
        const float4* wp4 = (const float4*)wp;
        const float4* bp4 = (const float4*)bp;
        float an[EMB];
#pragma unroll
        for (int d = 0; d < EMB; ++d) an[d] = adj[n * EMB + d];
        float4 w[5];
#pragma unroll
        for (int c = 0; c < 5; ++c) { w[c].x = w[c].y = w[c].z = w[c].w = 0.f; }
#pragma unroll
        for (int d = 0; d < EMB; ++d) {
            float a = an[d];
#pragma unroll
            for (int c = 0; c < 4; ++c) {
                float4 p = wp4[(d * 4 + c) * 16 + og];
                w[c].x += a * p.x; w[c].y += a * p.y; w[c].z += a * p.z; w[c].w += a * p.w;
            }
            float4 pb = bp4[d * 16 + og];
            w[4].x += a * pb.x; w[4].y += a * pb.y; w[4].z += a * pb.z; w[4].w += a * pb.w;
        }
#pragma unroll
        for (int c = 0; c < 5; ++c) {
            ushort4 pk;
            pk.x = f2b(w[c].x); pk.y = f2b(w[c].y); pk.z = f2b(w[c].z); pk.w = f2b(w[c].w);
            *(ushort4*)(WbufB + (size_t)n * 320 + c * 64 + og * 4) = pk;
        }
    }
}

// ---------------------------------------------------------------------------
// K2: MFMA flash propagation. Issue-early/consume-late single-buffer V +
// one-ahead A prefetch; ~116 VGPR -> 4 waves/SIMD (vs 3 with ping-pong).
// 4 waves/block, 32 n per wave, barrier/LDS/atomic-free. bf16 partials out.
// ---------------------------------------------------------------------------
__launch_bounds__(256, 4)
__global__ void k_prop(const short* __restrict__ Afrag, const short* __restrict__ adjS,
                       const short* __restrict__ VTf,
                       short* __restrict__ ynum, float* __restrict__ den) {
    const int t = threadIdx.x;
    const int wv = t >> 6;
    const int lane = t & 63;
    const int l = lane & 15;
    const int q = lane >> 4;
    const int n0 = blockIdx.x * 128 + wv * 32;
    const int cbeg = blockIdx.y * (NN / MS / 32);   // 16 c-subtiles per block
    const int cend = cbeg + (NN / MS / 32);

    // loop-invariant score B-fragments (log2e-scaled), k>=16 zeroed
    bf16x8 Bn[2];
    bf16x8 zv = {0, 0, 0, 0, 0, 0, 0, 0};
#pragma unroll
    for (int s = 0; s < 2; ++s) {
        const short* src = adjS + (size_t)(n0 + 16 * s + l) * EMB + (q & 1) * 8;
        bf16x8 v = *(const bf16x8*)src;
        Bn[s] = (q < 2) ? v : zv;
    }
    const short one = (short)0x3F80;
    bf16x8 ones = {one, one, one, one, one, one, one, one};

    f32x4 acc[4][2];
    f32x4 dacc[2];
#pragma unroll
    for (int u = 0; u < 4; ++u)
#pragma unroll
        for (int s = 0; s < 2; ++s) { acc[u][s][0] = acc[u][s][1] = acc[u][s][2] = acc[u][s][3] = 0.f; }
#pragma unroll
    for (int s = 0; s < 2; ++s) { dacc[s][0] = dacc[s][1] = dacc[s][2] = dacc[s][3] = 0.f; }

    const short* Ap = Afrag + (size_t)lane * 8;   // + cg*1024 + h*512
    const short* Vp = VTf + (size_t)lane * 8;     // + cg*2048 + u*512

    // prologue: A fragments for first subtile
    bf16x8 aCur0 = *(const bf16x8*)(Ap + (size_t)cbeg * 1024);
    bf16x8 aCur1 = *(const bf16x8*)(Ap + (size_t)cbeg * 1024 + 512);

    for (int cg = cbeg; cg < cend; ++cg) {
        // issue V loads for THIS subtile and A loads for the NEXT subtile
        // (both consumed after ~300 cycles of score MFMA + exp/pack below,
        //  which covers the ~200-cycle L2 hit latency)
        bf16x8 v0 = *(const bf16x8*)(Vp + (size_t)cg * 2048);
        bf16x8 v1 = *(const bf16x8*)(Vp + (size_t)cg * 2048 + 512);
        bf16x8 v2 = *(const bf16x8*)(Vp + (size_t)cg * 2048 + 1024);
        bf16x8 v3 = *(const bf16x8*)(Vp + (size_t)cg * 2048 + 1536);
        const int cgn = (cg + 1 < cend) ? cg + 1 : cbeg;   // clamped redundant last
        bf16x8 aN0 = *(const bf16x8*)(Ap + (size_t)cgn * 1024);
        bf16x8 aN1 = *(const bf16x8*)(Ap + (size_t)cgn * 1024 + 512);

        f32x4 z = {0.f, 0.f, 0.f, 0.f};
        f32x4 S0[2], S1[2];
#pragma unroll
        for (int s = 0; s < 2; ++s) {
            S0[s] = __builtin_amdgcn_mfma_f32_16x16x32_bf16(aCur0, Bn[s], z, 0, 0, 0);
            S1[s] = __builtin_amdgcn_mfma_f32_16x16x32_bf16(aCur1, Bn[s], z, 0, 0, 0);
        }
#pragma unroll
        for (int s = 0; s < 2; ++s) {
            unsigned w0[4], w1[4];
#pragma unroll
            for (int r = 0; r < 4; ++r) {
                union { float f; unsigned u; } p0, p1;
                p0.f = __builtin_amdgcn_exp2f(fmaxf(S0[s][r], 0.f));
                p1.f = __builtin_amdgcn_exp2f(fmaxf(S1[s][r], 0.f));
                w0[r] = p0.u;      // j = r      (h=0)
                w1[r] = p1.u;      // j = 4 + r  (h=1)
            }
            union { bf16x8 v; unsigned d[4]; } pf;
            pf.d[0] = packbf(w0[0], w0[1]);
            pf.d[1] = packbf(w0[2], w0[3]);
            pf.d[2] = packbf(w1[0], w1[1]);
            pf.d[3] = packbf(w1[2], w1[3]);
            acc[0][s] = __builtin_amdgcn_mfma_f32_16x16x32_bf16(v0, pf.v, acc[0][s], 0, 0, 0);
            acc[1][s] = __builtin_amdgcn_mfma_f32_16x16x32_bf16(v1, pf.v, acc[1][s], 0, 0, 0);
            acc[2][s] = __builtin_amdgcn_mfma_f32_16x16x32_bf16(v2, pf.v, acc[2][s], 0, 0, 0);
            acc[3][s] = __builtin_amdgcn_mfma_f32_16x16x32_bf16(v3, pf.v, acc[3][s], 0, 0, 0);
            dacc[s] = __builtin_amdgcn_mfma_f32_16x16x32_bf16(ones, pf.v, dacc[s], 0, 0, 0);
        }
        aCur0 = aN0;
        aCur1 = aN1;
    }

    // stores: bf16 partials [split][n][64]; den rows all equal -> dacc[s][0]
    short* yp = ynum + (size_t)blockIdx.y * NN * HID;
#pragma unroll
    for (int s = 0; s < 2; ++s) {
        const int n = n0 + 16 * s + l;
#pragma unroll
        for (int u = 0; u < 4; ++u) {
            union { float f; unsigned u; } a0, a1, a2, a3;
            a0.f = acc[u][s][0]; a1.f = acc[u][s][1]; a2.f = acc[u][s][2]; a3.f = acc[u][s][3];
            uint2 pk;
            pk.x = packbf(a0.u, a1.u);
            pk.y = packbf(a2.u, a3.u);
            *(uint2*)(yp + (size_t)n * HID + 16 * u + 4 * q) = pk;
        }
        if (q == 0) den[(size_t)blockIdx.y * NN + n] = dacc[s][0];
    }
}

// ---------------------------------------------------------------------------
// K3: epilogue. 16 nodes/block; reduce MS bf16 partials, normalize, apply
// bf16 per-node weights, nontemporal write out [32][8192][64] fp32.
// ---------------------------------------------------------------------------
__global__ void k_epi(const unsigned short* __restrict__ WbufB, const float* __restrict__ x,
                      const short* __restrict__ ynum, const float* __restrict__ den,
                      float* __restrict__ out) {
    const int nl = threadIdx.x >> 4, og = threadIdx.x & 15;
    const int n = blockIdx.x * 16 + nl;
    __shared__ float xl[16][68];
    __shared__ float yl[16][68];

    float4 W[5];
#pragma unroll
    for (int c = 0; c < 5; ++c) {
        ushort4 pw = *(const ushort4*)(WbufB + (size_t)n * 320 + c * 64 + og * 4);
        union { unsigned u; float f; } c0, c1, c2, c3;
        c0.u = (unsigned)pw.x << 16; c1.u = (unsigned)pw.y << 16;
        c2.u = (unsigned)pw.z << 16; c3.u = (unsigned)pw.w << 16;
        W[c].x = c0.f; W[c].y = c1.f; W[c].z = c2.f; W[c].w = c3.f;
    }

    float4 ysum; ysum.x = ysum.y = ysum.z = ysum.w = 0.f;
    float dsum = 0.f;
#pragma unroll
    for (int s = 0; s < MS; ++s) {
        ushort4 p = *(const ushort4*)(ynum + ((size_t)s * NN + n) * HID + og * 4);
        union { unsigned u; float f; } c0, c1, c2, c3;
        c0.u = (unsigned)p.x << 16; c1.u = (unsigned)p.y << 16;
        c2.u = (unsigned)p.z << 16; c3.u = (unsigned)p.w << 16;
        ysum.x += c0.f; ysum.y += c1.f; ysum.z += c2.f; ysum.w += c3.f;
        dsum += den[(size_t)s * NN + n];
    }
    float rden = 1.f / dsum;
    *(float4*)&yl[nl][og * 4] = make_float4(ysum.x * rden, ysum.y * rden, ysum.z * rden, ysum.w * rden);

    float2 x0 = *(const float2*)(x + ((size_t)(og * 2) * NN + n) * 2);
    float2 x1 = *(const float2*)(x + ((size_t)(og * 2 + 1) * NN + n) * 2);
    xl[nl][og * 4 + 0] = x0.x; xl[nl][og * 4 + 1] = x0.y;
    xl[nl][og * 4 + 2] = x1.x; xl[nl][og * 4 + 3] = x1.y;
    __syncthreads();

#pragma unroll 4
    for (int b = 0; b < BB; ++b) {
        float xb0 = xl[nl][2 * b], xb1 = xl[nl][2 * b + 1];
        float yb0 = yl[nl][2 * b], yb1 = yl[nl][2 * b + 1];
        f32x4 o4;
        o4[0] = xb0 * W[0].x + xb1 * W[1].x + yb0 * W[2].x + yb1 * W[3].x + W[4].x;
        o4[1] = xb0 * W[0].y + xb1 * W[1].y + yb0 * W[2].y + yb1 * W[3].y + W[4].y;
        o4[2] = xb0 * W[0].z + xb1 * W[1].z + yb0 * W[2].z + yb1 * W[3].z + W[4].z;
        o4[3] = xb0 * W[0].w + xb1 * W[1].w + yb0 * W[2].w + yb1 * W[3].w + W[4].w;
        __builtin_nontemporal_store(o4, (f32x4*)(out + ((size_t)b * NN + n) * HID + og * 4));
    }
}

// ---------------------------------------------------------------------------
extern "C" void kernel_launch(void* const* d_in, const int* in_sizes, int n_in,
                              void* d_out, int out_size, void* d_ws, size_t ws_size,
                              hipStream_t stream) {
    const float* x   = (const float*)d_in[0];   // [32, 8192, 2]
    const float* adj = (const float*)d_in[1];   // [8192, 16]
    const float* wp  = (const float*)d_in[2];   // [16, 2, 2, 64]
    const float* bp  = (const float*)d_in[3];   // [16, 64]
    float* out = (float*)d_out;                 // [32, 8192, 64]

    char* w = (char*)d_ws;
    short* VTf   = (short*)w;                                   // 1 MB
    short* Afrag = VTf + (size_t)256 * 4 * 64 * 8;              // 512 KB
    short* adjS  = Afrag + (size_t)256 * 2 * 64 * 8;            // 256 KB
    unsigned short* WbufB = (unsigned short*)(adjS + (size_t)NN * EMB);  // 5.25 MB
    short* ynum  = (short*)(WbufB + (size_t)NN * 320);          // 16 MB
    float* den   = (float*)(ynum + (size_t)MS * NN * HID);      // 512 KB

    k_build<<<1024, 256, 0, stream>>>(x, adj, wp, bp, VTf, Afrag, adjS, WbufB);
    k_prop<<<dim3(NN / 128, MS), 256, 0, stream>>>(Afrag, adjS, VTf, ynum, den);
    k_epi<<<NN / 16, 256, 0, stream>>>(WbufB, x, ynum, den, out);
}

// Round 3
// 116.582 us; speedup vs baseline: 1.0462x; 1.0410x over previous
//
#include <hip/hip_runtime.h>

#define NN 8192
#define BB 32
#define EMB 16
#define HID 64

typedef __attribute__((ext_vector_type(8))) short bf16x8;
typedef __attribute__((ext_vector_type(4))) float f32x4;

static __device__ inline unsigned short f2b(float f) {   // round-to-nearest-even
    union { float f; unsigned u; } v; v.f = f;
    return (unsigned short)((v.u + 0x7fffu + ((v.u >> 16) & 1u)) >> 16);
}

// pack two fp32 (truncate) into one dword of bf16: [hi16(odd) : hi16(even)]
static __device__ inline unsigned packbf(unsigned e_even, unsigned e_odd) {
#if __has_builtin(__builtin_amdgcn_perm)
    return __builtin_amdgcn_perm(e_odd, e_even, 0x07060302u);
#else
    return (e_odd & 0xFFFF0000u) | (e_even >> 16);
#endif
}

// ---------------------------------------------------------------------------
// K1: fused operand prep (all stored in MFMA-fragment lane order).
//  bx [0,256):    VTf[c][u][lane]  : V fragments (PV A-operand)
//  bx [256,384):  Afrag[c][h][lane]: adj m-rows (score A-operand, permuted)
//  bx [384,512):  adjS[n][d] = bf16(adj*log2e)  (score B side, row-major)
//  bx [512,1024): WbufB[n][c*64+o] bf16 node-adaptive weights {x0,x1,y0,y1,b}
// ---------------------------------------------------------------------------
__global__ void k_build(const float* __restrict__ x, const float* __restrict__ adj,
                        const float* __restrict__ wp, const float* __restrict__ bp,
                        short* __restrict__ VTf, short* __restrict__ Afrag,
                        short* __restrict__ adjS, unsigned short* __restrict__ WbufB) {
    const int t = threadIdx.x;
    const int bx = blockIdx.x;
    if (bx < 256) {
        const int c = bx;
        const int u = t >> 6, lane = t & 63, l = lane & 15, q = lane >> 4;
        const int j = 16 * u + l, b = j >> 1, ch = j & 1;
        const int m0 = 32 * c + 8 * q;
        const float* xp = x + (size_t)b * (NN * 2) + m0 * 2;
        uint4 d;
        unsigned dd[4];
#pragma unroll
        for (int i = 0; i < 4; ++i) {
            float4 xx = *(const float4*)(xp + 4 * i);
            float v0 = ch ? xx.y : xx.x;
            float v1 = ch ? xx.w : xx.z;
            dd[i] = (unsigned)f2b(v0) | ((unsigned)f2b(v1) << 16);
        }
        d.x = dd[0]; d.y = dd[1]; d.z = dd[2]; d.w = dd[3];
        *(uint4*)(VTf + ((size_t)(c * 4 + u) * 64 + lane) * 8) = d;
    } else if (bx < 384) {
        const int cc = t >> 7, tt = t & 127;
        const int c = (bx - 256) * 2 + cc;
        const int h = tt >> 6, lane = tt & 63, l = lane & 15, q = lane >> 4;
        const int row = 32 * c + 8 * (l >> 2) + (l & 3) + 4 * h;
        const float* ap = adj + (size_t)row * EMB + (q & 1) * 8;
        float4 a0 = *(const float4*)(ap);
        float4 a1 = *(const float4*)(ap + 4);
        uint4 d;
        d.x = (unsigned)f2b(a0.x) | ((unsigned)f2b(a0.y) << 16);
        d.y = (unsigned)f2b(a0.z) | ((unsigned)f2b(a0.w) << 16);
        d.z = (unsigned)f2b(a1.x) | ((unsigned)f2b(a1.y) << 16);
        d.w = (unsigned)f2b(a1.z) | ((unsigned)f2b(a1.w) << 16);
        *(uint4*)(Afrag + ((size_t)(c * 2 + h) * 64 + lane) * 8) = d;
    } else if (bx < 512) {
        const float L2E = 1.4426950408889634f;
        int idx = (bx - 384) * 256 + t;
        float4 aa = *(const float4*)(adj + (size_t)idx * 4);
        uint2 us;
        us.x = (unsigned)f2b(aa.x * L2E) | ((unsigned)f2b(aa.y * L2E) << 16);
        us.y = (unsigned)f2b(aa.z * L2E) | ((unsigned)f2b(aa.w * L2E) << 16);
        *(uint2*)(adjS + (size_t)idx * 4) = us;
    } else {
        const int nl = t >> 4, og = t & 15;
        const int n = (bx - 512) * 16 + nl;
        const float4* wp4 = (const float4*)wp;
        const float4* bp4 = (const float4*)bp;
        float an[EMB];
#pragma unroll
        for (int d = 0; d < EMB; ++d) an[d] = adj[n * EMB + d];
        float4 w[5];
#pragma unroll
        for (int c = 0; c < 5; ++c) { w[c].x = w[c].y = w[c].z = w[c].w = 0.f; }
#pragma unroll
        for (int d = 0; d < EMB; ++d) {
            float a = an[d];
#pragma unroll
            for (int c = 0; c < 4; ++c) {
                float4 p = wp4[(d * 4 + c) * 16 + og];
                w[c].x += a * p.x; w[c].y += a * p.y; w[c].z += a * p.z; w[c].w += a * p.w;
            }
            float4 pb = bp4[d * 16 + og];
            w[4].x += a * pb.x; w[4].y += a * pb.y; w[4].z += a * pb.z; w[4].w += a * pb.w;
        }
#pragma unroll
        for (int c = 0; c < 5; ++c) {
            ushort4 pk;
            pk.x = f2b(w[c].x); pk.y = f2b(w[c].y); pk.z = f2b(w[c].z); pk.w = f2b(w[c].w);
            *(ushort4*)(WbufB + (size_t)n * 320 + c * 64 + og * 4) = pk;
        }
    }
}

// ---------------------------------------------------------------------------
// K2 (fused): flash propagation + normalization + weight apply + final write.
// 256 blocks x 512 threads. Block owns a 32-node n-tile and the FULL m-range;
// the 8 waves split m into 32 subtiles each. Partials (bf16 num / f32 den)
// meet in LDS -> one barrier -> old-epilogue body. No global partial traffic,
// no third kernel.
// ---------------------------------------------------------------------------
__launch_bounds__(512, 2)
__global__ void k_fused(const short* __restrict__ Afrag, const short* __restrict__ adjS,
                        const short* __restrict__ VTf,
                        const unsigned short* __restrict__ WbufB, const float* __restrict__ x,
                        float* __restrict__ out) {
    const int t = threadIdx.x;
    const int wv = t >> 6;
    const int lane = t & 63;
    const int l = lane & 15;
    const int q = lane >> 4;
    const int n0 = blockIdx.x * 32;                 // block's n-tile (32 nodes)
    const int cbeg = wv * 32;                       // wave's m-range: 32 subtiles
    const int cend = cbeg + 32;

    __shared__ __align__(16) unsigned short ysl[8][32][68];  // bf16 num partials [slot][n][j] (pad 68)
    __shared__ float dsl[8][32];                             // den partials
    __shared__ float xl[32][68];
    __shared__ float ylf[32][68];

    // loop-invariant score B-fragments (log2e-scaled), k>=16 zeroed
    bf16x8 Bn[2];
    bf16x8 zv = {0, 0, 0, 0, 0, 0, 0, 0};
#pragma unroll
    for (int s = 0; s < 2; ++s) {
        const short* src = adjS + (size_t)(n0 + 16 * s + l) * EMB + (q & 1) * 8;
        bf16x8 v = *(const bf16x8*)src;
        Bn[s] = (q < 2) ? v : zv;
    }
    const short one = (short)0x3F80;
    bf16x8 ones = {one, one, one, one, one, one, one, one};

    f32x4 acc[4][2];
    f32x4 dacc[2];
#pragma unroll
    for (int u = 0; u < 4; ++u)
#pragma unroll
        for (int s = 0; s < 2; ++s) { acc[u][s][0] = acc[u][s][1] = acc[u][s][2] = acc[u][s][3] = 0.f; }
#pragma unroll
    for (int s = 0; s < 2; ++s) { dacc[s][0] = dacc[s][1] = dacc[s][2] = dacc[s][3] = 0.f; }

    const short* Ap = Afrag + (size_t)lane * 8;   // + cg*1024 + h*512
    const short* Vp = VTf + (size_t)lane * 8;     // + cg*2048 + u*512

    // prologue: A fragments for first subtile
    bf16x8 aCur0 = *(const bf16x8*)(Ap + (size_t)cbeg * 1024);
    bf16x8 aCur1 = *(const bf16x8*)(Ap + (size_t)cbeg * 1024 + 512);

    for (int cg = cbeg; cg < cend; ++cg) {
        // issue V loads for THIS subtile and A loads for the NEXT subtile;
        // both consumed after the score MFMA + exp/pack below.
        bf16x8 v0 = *(const bf16x8*)(Vp + (size_t)cg * 2048);
        bf16x8 v1 = *(const bf16x8*)(Vp + (size_t)cg * 2048 + 512);
        bf16x8 v2 = *(const bf16x8*)(Vp + (size_t)cg * 2048 + 1024);
        bf16x8 v3 = *(const bf16x8*)(Vp + (size_t)cg * 2048 + 1536);
        const int cgn = (cg + 1 < cend) ? cg + 1 : cbeg;   // clamped redundant last
        bf16x8 aN0 = *(const bf16x8*)(Ap + (size_t)cgn * 1024);
        bf16x8 aN1 = *(const bf16x8*)(Ap + (size_t)cgn * 1024 + 512);

        f32x4 z = {0.f, 0.f, 0.f, 0.f};
        f32x4 S0[2], S1[2];
#pragma unroll
        for (int s = 0; s < 2; ++s) {
            S0[s] = __builtin_amdgcn_mfma_f32_16x16x32_bf16(aCur0, Bn[s], z, 0, 0, 0);
            S1[s] = __builtin_amdgcn_mfma_f32_16x16x32_bf16(aCur1, Bn[s], z, 0, 0, 0);
        }
#pragma unroll
        for (int s = 0; s < 2; ++s) {
            unsigned w0[4], w1[4];
#pragma unroll
            for (int r = 0; r < 4; ++r) {
                union { float f; unsigned u; } p0, p1;
                p0.f = __builtin_amdgcn_exp2f(fmaxf(S0[s][r], 0.f));
                p1.f = __builtin_amdgcn_exp2f(fmaxf(S1[s][r], 0.f));
                w0[r] = p0.u;      // j = r      (h=0)
                w1[r] = p1.u;      // j = 4 + r  (h=1)
            }
            union { bf16x8 v; unsigned d[4]; } pf;
            pf.d[0] = packbf(w0[0], w0[1]);
            pf.d[1] = packbf(w0[2], w0[3]);
            pf.d[2] = packbf(w1[0], w1[1]);
            pf.d[3] = packbf(w1[2], w1[3]);
            acc[0][s] = __builtin_amdgcn_mfma_f32_16x16x32_bf16(v0, pf.v, acc[0][s], 0, 0, 0);
            acc[1][s] = __builtin_amdgcn_mfma_f32_16x16x32_bf16(v1, pf.v, acc[1][s], 0, 0, 0);
            acc[2][s] = __builtin_amdgcn_mfma_f32_16x16x32_bf16(v2, pf.v, acc[2][s], 0, 0, 0);
            acc[3][s] = __builtin_amdgcn_mfma_f32_16x16x32_bf16(v3, pf.v, acc[3][s], 0, 0, 0);
            dacc[s] = __builtin_amdgcn_mfma_f32_16x16x32_bf16(ones, pf.v, dacc[s], 0, 0, 0);
        }
        aCur0 = aN0;
        aCur1 = aN1;
    }

    // dump this wave's partial (bf16 num, f32 den) into its LDS slot
#pragma unroll
    for (int s = 0; s < 2; ++s) {
        const int nl_w = 16 * s + l;
#pragma unroll
        for (int u = 0; u < 4; ++u) {
            union { float f; unsigned u; } a0, a1, a2, a3;
            a0.f = acc[u][s][0]; a1.f = acc[u][s][1]; a2.f = acc[u][s][2]; a3.f = acc[u][s][3];
            uint2 pk;
            pk.x = packbf(a0.u, a1.u);
            pk.y = packbf(a2.u, a3.u);
            *(uint2*)&ysl[wv][nl_w][16 * u + 4 * q] = pk;
        }
        if (q == 0) dsl[wv][nl_w] = dacc[s][0];
    }
    __syncthreads();

    // ---- epilogue (old k_epi body, partials from LDS) ----
    const int nl = t >> 4, og = t & 15;
    const int n = n0 + nl;

    float4 W[5];
#pragma unroll
    for (int c = 0; c < 5; ++c) {
        ushort4 pw = *(const ushort4*)(WbufB + (size_t)n * 320 + c * 64 + og * 4);
        union { unsigned u; float f; } c0, c1, c2, c3;
        c0.u = (unsigned)pw.x << 16; c1.u = (unsigned)pw.y << 16;
        c2.u = (unsigned)pw.z << 16; c3.u = (unsigned)pw.w << 16;
        W[c].x = c0.f; W[c].y = c1.f; W[c].z = c2.f; W[c].w = c3.f;
    }

    float4 ysum; ysum.x = ysum.y = ysum.z = ysum.w = 0.f;
    float dsum = 0.f;
#pragma unroll
    for (int s = 0; s < 8; ++s) {
        ushort4 p = *(const ushort4*)&ysl[s][nl][og * 4];
        union { unsigned u; float f; } c0, c1, c2, c3;
        c0.u = (unsigned)p.x << 16; c1.u = (unsigned)p.y << 16;
        c2.u = (unsigned)p.z << 16; c3.u = (unsigned)p.w << 16;
        ysum.x += c0.f; ysum.y += c1.f; ysum.z += c2.f; ysum.w += c3.f;
        dsum += dsl[s][nl];
    }
    float rden = 1.f / dsum;
    *(float4*)&ylf[nl][og * 4] = make_float4(ysum.x * rden, ysum.y * rden, ysum.z * rden, ysum.w * rden);

    float2 x0 = *(const float2*)(x + ((size_t)(og * 2) * NN + n) * 2);
    float2 x1 = *(const float2*)(x + ((size_t)(og * 2 + 1) * NN + n) * 2);
    xl[nl][og * 4 + 0] = x0.x; xl[nl][og * 4 + 1] = x0.y;
    xl[nl][og * 4 + 2] = x1.x; xl[nl][og * 4 + 3] = x1.y;
    __syncthreads();

#pragma unroll 4
    for (int b = 0; b < BB; ++b) {
        float xb0 = xl[nl][2 * b], xb1 = xl[nl][2 * b + 1];
        float yb0 = ylf[nl][2 * b], yb1 = ylf[nl][2 * b + 1];
        f32x4 o4;
        o4[0] = xb0 * W[0].x + xb1 * W[1].x + yb0 * W[2].x + yb1 * W[3].x + W[4].x;
        o4[1] = xb0 * W[0].y + xb1 * W[1].y + yb0 * W[2].y + yb1 * W[3].y + W[4].y;
        o4[2] = xb0 * W[0].z + xb1 * W[1].z + yb0 * W[2].z + yb1 * W[3].z + W[4].z;
        o4[3] = xb0 * W[0].w + xb1 * W[1].w + yb0 * W[2].w + yb1 * W[3].w + W[4].w;
        __builtin_nontemporal_store(o4, (f32x4*)(out + ((size_t)b * NN + n) * HID + og * 4));
    }
}

// ---------------------------------------------------------------------------
extern "C" void kernel_launch(void* const* d_in, const int* in_sizes, int n_in,
                              void* d_out, int out_size, void* d_ws, size_t ws_size,
                              hipStream_t stream) {
    const float* x   = (const float*)d_in[0];   // [32, 8192, 2]
    const float* adj = (const float*)d_in[1];   // [8192, 16]
    const float* wp  = (const float*)d_in[2];   // [16, 2, 2, 64]
    const float* bp  = (const float*)d_in[3];   // [16, 64]
    float* out = (float*)d_out;                 // [32, 8192, 64]

    char* w = (char*)d_ws;
    short* VTf   = (short*)w;                                   // 1 MB
    short* Afrag = VTf + (size_t)256 * 4 * 64 * 8;              // 512 KB
    short* adjS  = Afrag + (size_t)256 * 2 * 64 * 8;            // 256 KB
    unsigned short* WbufB = (unsigned short*)(adjS + (size_t)NN * EMB);  // 5.25 MB

    k_build<<<1024, 256, 0, stream>>>(x, adj, wp, bp, VTf, Afrag, adjS, WbufB);
    k_fused<<<NN / 32, 512, 0, stream>>>(Afrag, adjS, VTf, WbufB, x, out);
}

// Round 4
// 116.495 us; speedup vs baseline: 1.0470x; 1.0008x over previous
//
#include <hip/hip_runtime.h>

#define NN 8192
#define BB 32
#define EMB 16
#define HID 64

typedef __attribute__((ext_vector_type(8))) short bf16x8;
typedef __attribute__((ext_vector_type(4))) float f32x4;

static __device__ inline unsigned short f2b(float f) {   // round-to-nearest-even
    union { float f; unsigned u; } v; v.f = f;
    return (unsigned short)((v.u + 0x7fffu + ((v.u >> 16) & 1u)) >> 16);
}

// pack two fp32 (truncate) into one dword of bf16: [hi16(odd) : hi16(even)]
static __device__ inline unsigned packbf(unsigned e_even, unsigned e_odd) {
#if __has_builtin(__builtin_amdgcn_perm)
    return __builtin_amdgcn_perm(e_odd, e_even, 0x07060302u);
#else
    return (e_odd & 0xFFFF0000u) | (e_even >> 16);
#endif
}

// ---------------------------------------------------------------------------
// K1: fused operand prep (all stored in MFMA-fragment lane order).
//  bx [0,256):    VTf[c][u][lane]  : V fragments (PV A-operand)
//  bx [256,384):  Afrag[c][h][lane]: adj m-rows (score A-operand, permuted)
//  bx [384,512):  adjS[n][d] = bf16(adj*log2e)  (score B side, row-major)
//  bx [512,1024): WbufB[n][c*64+o] bf16 node-adaptive weights {x0,x1,y0,y1,b}
// ---------------------------------------------------------------------------
__global__ void k_build(const float* __restrict__ x, const float* __restrict__ adj,
                        const float* __restrict__ wp, const float* __restrict__ bp,
                        short* __restrict__ VTf, short* __restrict__ Afrag,
                        short* __restrict__ adjS, unsigned short* __restrict__ WbufB) {
    const int t = threadIdx.x;
    const int bx = blockIdx.x;
    if (bx < 256) {
        const int c = bx;
        const int u = t >> 6, lane = t & 63, l = lane & 15, q = lane >> 4;
        const int j = 16 * u + l, b = j >> 1, ch = j & 1;
        const int m0 = 32 * c + 8 * q;
        const float* xp = x + (size_t)b * (NN * 2) + m0 * 2;
        uint4 d;
        unsigned dd[4];
#pragma unroll
        for (int i = 0; i < 4; ++i) {
            float4 xx = *(const float4*)(xp + 4 * i);
            float v0 = ch ? xx.y : xx.x;
            float v1 = ch ? xx.w : xx.z;
            dd[i] = (unsigned)f2b(v0) | ((unsigned)f2b(v1) << 16);
        }
        d.x = dd[0]; d.y = dd[1]; d.z = dd[2]; d.w = dd[3];
        *(uint4*)(VTf + ((size_t)(c * 4 + u) * 64 + lane) * 8) = d;
    } else if (bx < 384) {
        const int cc = t >> 7, tt = t & 127;
        const int c = (bx - 256) * 2 + cc;
        const int h = tt >> 6, lane = tt & 63, l = lane & 15, q = lane >> 4;
        const int row = 32 * c + 8 * (l >> 2) + (l & 3) + 4 * h;
        const float* ap = adj + (size_t)row * EMB + (q & 1) * 8;
        float4 a0 = *(const float4*)(ap);
        float4 a1 = *(const float4*)(ap + 4);
        uint4 d;
        d.x = (unsigned)f2b(a0.x) | ((unsigned)f2b(a0.y) << 16);
        d.y = (unsigned)f2b(a0.z) | ((unsigned)f2b(a0.w) << 16);
        d.z = (unsigned)f2b(a1.x) | ((unsigned)f2b(a1.y) << 16);
        d.w = (unsigned)f2b(a1.z) | ((unsigned)f2b(a1.w) << 16);
        *(uint4*)(Afrag + ((size_t)(c * 2 + h) * 64 + lane) * 8) = d;
    } else if (bx < 512) {
        const float L2E = 1.4426950408889634f;
        int idx = (bx - 384) * 256 + t;
        float4 aa = *(const float4*)(adj + (size_t)idx * 4);
        uint2 us;
        us.x = (unsigned)f2b(aa.x * L2E) | ((unsigned)f2b(aa.y * L2E) << 16);
        us.y = (unsigned)f2b(aa.z * L2E) | ((unsigned)f2b(aa.w * L2E) << 16);
        *(uint2*)(adjS + (size_t)idx * 4) = us;
    } else {
        const int nl = t >> 4, og = t & 15;
        const int n = (bx - 512) * 16 + nl;
        const float4* wp4 = (const float4*)wp;
        const float4* bp4 = (const float4*)bp;
        float an[EMB];
#pragma unroll
        for (int d = 0; d < EMB; ++d) an[d] = adj[n * EMB + d];
        float4 w[5];
#pragma unroll
        for (int c = 0; c < 5; ++c) { w[c].x = w[c].y = w[c].z = w[c].w = 0.f; }
#pragma unroll
        for (int d = 0; d < EMB; ++d) {
            float a = an[d];
#pragma unroll
            for (int c = 0; c < 4; ++c) {
                float4 p = wp4[(d * 4 + c) * 16 + og];
                w[c].x += a * p.x; w[c].y += a * p.y; w[c].z += a * p.z; w[c].w += a * p.w;
            }
            float4 pb = bp4[d * 16 + og];
            w[4].x += a * pb.x; w[4].y += a * pb.y; w[4].z += a * pb.z; w[4].w += a * pb.w;
        }
#pragma unroll
        for (int c = 0; c < 5; ++c) {
            ushort4 pk;
            pk.x = f2b(w[c].x); pk.y = f2b(w[c].y); pk.z = f2b(w[c].z); pk.w = f2b(w[c].w);
            *(ushort4*)(WbufB + (size_t)n * 320 + c * 64 + og * 4) = pk;
        }
    }
}

// ---------------------------------------------------------------------------
// K2 (fused): flash propagation + normalization + weight apply + final write.
// 256 blocks x 512 threads. Block owns a 32-node n-tile and the FULL m-range;
// the 8 waves split m into 32 subtiles each. Partials (bf16 num / f32 den)
// meet in LDS -> one barrier -> old-epilogue body.
// launch_bounds min-waves 2->1: the (512,2) declaration capped the allocator
// at 128 VGPR/wave, right at this loop's ~125-reg liveness -> suspected
// spill/scheduling wall (k_fused ~3x its L2/VALU floor). Cap now 256.
// ---------------------------------------------------------------------------
__launch_bounds__(512, 1)
__global__ void k_fused(const short* __restrict__ Afrag, const short* __restrict__ adjS,
                        const short* __restrict__ VTf,
                        const unsigned short* __restrict__ WbufB, const float* __restrict__ x,
                        float* __restrict__ out) {
    const int t = threadIdx.x;
    const int wv = t >> 6;
    const int lane = t & 63;
    const int l = lane & 15;
    const int q = lane >> 4;
    const int n0 = blockIdx.x * 32;                 // block's n-tile (32 nodes)
    const int cbeg = wv * 32;                       // wave's m-range: 32 subtiles
    const int cend = cbeg + 32;

    __shared__ __align__(16) unsigned short ysl[8][32][68];  // bf16 num partials [slot][n][j] (pad 68)
    __shared__ float dsl[8][32];                             // den partials
    __shared__ float xl[32][68];
    __shared__ float ylf[32][68];

    // loop-invariant score B-fragments (log2e-scaled), k>=16 zeroed
    bf16x8 Bn[2];
    bf16x8 zv = {0, 0, 0, 0, 0, 0, 0, 0};
#pragma unroll
    for (int s = 0; s < 2; ++s) {
        const short* src = adjS + (size_t)(n0 + 16 * s + l) * EMB + (q & 1) * 8;
        bf16x8 v = *(const bf16x8*)src;
        Bn[s] = (q < 2) ? v : zv;
    }
    const short one = (short)0x3F80;
    bf16x8 ones = {one, one, one, one, one, one, one, one};

    f32x4 acc[4][2];
    f32x4 dacc[2];
#pragma unroll
    for (int u = 0; u < 4; ++u)
#pragma unroll
        for (int s = 0; s < 2; ++s) { acc[u][s][0] = acc[u][s][1] = acc[u][s][2] = acc[u][s][3] = 0.f; }
#pragma unroll
    for (int s = 0; s < 2; ++s) { dacc[s][0] = dacc[s][1] = dacc[s][2] = dacc[s][3] = 0.f; }

    const short* Ap = Afrag + (size_t)lane * 8;   // + cg*1024 + h*512
    const short* Vp = VTf + (size_t)lane * 8;     // + cg*2048 + u*512

    // prologue: A fragments for first subtile
    bf16x8 aCur0 = *(const bf16x8*)(Ap + (size_t)cbeg * 1024);
    bf16x8 aCur1 = *(const bf16x8*)(Ap + (size_t)cbeg * 1024 + 512);

    for (int cg = cbeg; cg < cend; ++cg) {
        // issue V loads for THIS subtile and A loads for the NEXT subtile;
        // both consumed after the score MFMA + exp/pack below.
        bf16x8 v0 = *(const bf16x8*)(Vp + (size_t)cg * 2048);
        bf16x8 v1 = *(const bf16x8*)(Vp + (size_t)cg * 2048 + 512);
        bf16x8 v2 = *(const bf16x8*)(Vp + (size_t)cg * 2048 + 1024);
        bf16x8 v3 = *(const bf16x8*)(Vp + (size_t)cg * 2048 + 1536);
        const int cgn = (cg + 1 < cend) ? cg + 1 : cbeg;   // clamped redundant last
        bf16x8 aN0 = *(const bf16x8*)(Ap + (size_t)cgn * 1024);
        bf16x8 aN1 = *(const bf16x8*)(Ap + (size_t)cgn * 1024 + 512);

        f32x4 z = {0.f, 0.f, 0.f, 0.f};
        f32x4 S0[2], S1[2];
#pragma unroll
        for (int s = 0; s < 2; ++s) {
            S0[s] = __builtin_amdgcn_mfma_f32_16x16x32_bf16(aCur0, Bn[s], z, 0, 0, 0);
            S1[s] = __builtin_amdgcn_mfma_f32_16x16x32_bf16(aCur1, Bn[s], z, 0, 0, 0);
        }
#pragma unroll
        for (int s = 0; s < 2; ++s) {
            unsigned w0[4], w1[4];
#pragma unroll
            for (int r = 0; r < 4; ++r) {
                union { float f; unsigned u; } p0, p1;
                p0.f = __builtin_amdgcn_exp2f(fmaxf(S0[s][r], 0.f));
                p1.f = __builtin_amdgcn_exp2f(fmaxf(S1[s][r], 0.f));
                w0[r] = p0.u;      // j = r      (h=0)
                w1[r] = p1.u;      // j = 4 + r  (h=1)
            }
            union { bf16x8 v; unsigned d[4]; } pf;
            pf.d[0] = packbf(w0[0], w0[1]);
            pf.d[1] = packbf(w0[2], w0[3]);
            pf.d[2] = packbf(w1[0], w1[1]);
            pf.d[3] = packbf(w1[2], w1[3]);
            acc[0][s] = __builtin_amdgcn_mfma_f32_16x16x32_bf16(v0, pf.v, acc[0][s], 0, 0, 0);
            acc[1][s] = __builtin_amdgcn_mfma_f32_16x16x32_bf16(v1, pf.v, acc[1][s], 0, 0, 0);
            acc[2][s] = __builtin_amdgcn_mfma_f32_16x16x32_bf16(v2, pf.v, acc[2][s], 0, 0, 0);
            acc[3][s] = __builtin_amdgcn_mfma_f32_16x16x32_bf16(v3, pf.v, acc[3][s], 0, 0, 0);
            dacc[s] = __builtin_amdgcn_mfma_f32_16x16x32_bf16(ones, pf.v, dacc[s], 0, 0, 0);
        }
        aCur0 = aN0;
        aCur1 = aN1;
    }

    // dump this wave's partial (bf16 num, f32 den) into its LDS slot
#pragma unroll
    for (int s = 0; s < 2; ++s) {
        const int nl_w = 16 * s + l;
#pragma unroll
        for (int u = 0; u < 4; ++u) {
            union { float f; unsigned u; } a0, a1, a2, a3;
            a0.f = acc[u][s][0]; a1.f = acc[u][s][1]; a2.f = acc[u][s][2]; a3.f = acc[u][s][3];
            uint2 pk;
            pk.x = packbf(a0.u, a1.u);
            pk.y = packbf(a2.u, a3.u);
            *(uint2*)&ysl[wv][nl_w][16 * u + 4 * q] = pk;
        }
        if (q == 0) dsl[wv][nl_w] = dacc[s][0];
    }
    __syncthreads();

    // ---- epilogue (old k_epi body, partials from LDS) ----
    const int nl = t >> 4, og = t & 15;
    const int n = n0 + nl;

    float4 W[5];
#pragma unroll
    for (int c = 0; c < 5; ++c) {
        ushort4 pw = *(const ushort4*)(WbufB + (size_t)n * 320 + c * 64 + og * 4);
        union { unsigned u; float f; } c0, c1, c2, c3;
        c0.u = (unsigned)pw.x << 16; c1.u = (unsigned)pw.y << 16;
        c2.u = (unsigned)pw.z << 16; c3.u = (unsigned)pw.w << 16;
        W[c].x = c0.f; W[c].y = c1.f; W[c].z = c2.f; W[c].w = c3.f;
    }

    float4 ysum; ysum.x = ysum.y = ysum.z = ysum.w = 0.f;
    float dsum = 0.f;
#pragma unroll
    for (int s = 0; s < 8; ++s) {
        ushort4 p = *(const ushort4*)&ysl[s][nl][og * 4];
        union { unsigned u; float f; } c0, c1, c2, c3;
        c0.u = (unsigned)p.x << 16; c1.u = (unsigned)p.y << 16;
        c2.u = (unsigned)p.z << 16; c3.u = (unsigned)p.w << 16;
        ysum.x += c0.f; ysum.y += c1.f; ysum.z += c2.f; ysum.w += c3.f;
        dsum += dsl[s][nl];
    }
    float rden = 1.f / dsum;
    *(float4*)&ylf[nl][og * 4] = make_float4(ysum.x * rden, ysum.y * rden, ysum.z * rden, ysum.w * rden);

    float2 x0 = *(const float2*)(x + ((size_t)(og * 2) * NN + n) * 2);
    float2 x1 = *(const float2*)(x + ((size_t)(og * 2 + 1) * NN + n) * 2);
    xl[nl][og * 4 + 0] = x0.x; xl[nl][og * 4 + 1] = x0.y;
    xl[nl][og * 4 + 2] = x1.x; xl[nl][og * 4 + 3] = x1.y;
    __syncthreads();

#pragma unroll 4
    for (int b = 0; b < BB; ++b) {
        float xb0 = xl[nl][2 * b], xb1 = xl[nl][2 * b + 1];
        float yb0 = ylf[nl][2 * b], yb1 = ylf[nl][2 * b + 1];
        f32x4 o4;
        o4[0] = xb0 * W[0].x + xb1 * W[1].x + yb0 * W[2].x + yb1 * W[3].x + W[4].x;
        o4[1] = xb0 * W[0].y + xb1 * W[1].y + yb0 * W[2].y + yb1 * W[3].y + W[4].y;
        o4[2] = xb0 * W[0].z + xb1 * W[1].z + yb0 * W[2].z + yb1 * W[3].z + W[4].z;
        o4[3] = xb0 * W[0].w + xb1 * W[1].w + yb0 * W[2].w + yb1 * W[3].w + W[4].w;
        __builtin_nontemporal_store(o4, (f32x4*)(out + ((size_t)b * NN + n) * HID + og * 4));
    }
}

// ---------------------------------------------------------------------------
extern "C" void kernel_launch(void* const* d_in, const int* in_sizes, int n_in,
                              void* d_out, int out_size, void* d_ws, size_t ws_size,
                              hipStream_t stream) {
    const float* x   = (const float*)d_in[0];   // [32, 8192, 2]
    const float* adj = (const float*)d_in[1];   // [8192, 16]
    const float* wp  = (const float*)d_in[2];   // [16, 2, 2, 64]
    const float* bp  = (const float*)d_in[3];   // [16, 64]
    float* out = (float*)d_out;                 // [32, 8192, 64]

    char* w = (char*)d_ws;
    short* VTf   = (short*)w;                                   // 1 MB
    short* Afrag = VTf + (size_t)256 * 4 * 64 * 8;              // 512 KB
    short* adjS  = Afrag + (size_t)256 * 2 * 64 * 8;            // 256 KB
    unsigned short* WbufB = (unsigned short*)(adjS + (size_t)NN * EMB);  // 5.25 MB

    k_build<<<1024, 256, 0, stream>>>(x, adj, wp, bp, VTf, Afrag, adjS, WbufB);
    k_fused<<<NN / 32, 512, 0, stream>>>(Afrag, adjS, VTf, WbufB, x, out);
}

// Round 5
// 111.433 us; speedup vs baseline: 1.0945x; 1.0454x over previous
//
#include <hip/hip_runtime.h>

#define NN 8192
#define BB 32
#define EMB 16
#define HID 64

typedef __attribute__((ext_vector_type(8))) short bf16x8;
typedef __attribute__((ext_vector_type(4))) float f32x4;

static __device__ inline unsigned short f2b(float f) {   // round-to-nearest-even
    union { float f; unsigned u; } v; v.f = f;
    return (unsigned short)((v.u + 0x7fffu + ((v.u >> 16) & 1u)) >> 16);
}

// pack two fp32 (truncate) into one dword of bf16: [hi16(odd) : hi16(even)]
static __device__ inline unsigned packbf(unsigned e_even, unsigned e_odd) {
#if __has_builtin(__builtin_amdgcn_perm)
    return __builtin_amdgcn_perm(e_odd, e_even, 0x07060302u);
#else
    return (e_odd & 0xFFFF0000u) | (e_even >> 16);
#endif
}

// ---------------------------------------------------------------------------
// K1: fragment prep (MFMA lane order). WbufB branch removed (W now computed
// in fp32 inside k_epi2 -> -10.5 MB HBM round trip).
//  bx [0,256):   VTf[c][u][lane]  : V fragments (PV A-operand)
//  bx [256,384): Afrag[c][h][lane]: adj m-rows (score A-operand, permuted)
//  bx [384,512): adjS[n][d] = bf16(adj*log2e)  (score B side, row-major)
// ---------------------------------------------------------------------------
__global__ void k_build(const float* __restrict__ x, const float* __restrict__ adj,
                        short* __restrict__ VTf, short* __restrict__ Afrag,
                        short* __restrict__ adjS) {
    const int t = threadIdx.x;
    const int bx = blockIdx.x;
    if (bx < 256) {
        const int c = bx;
        const int u = t >> 6, lane = t & 63, l = lane & 15, q = lane >> 4;
        const int j = 16 * u + l, b = j >> 1, ch = j & 1;
        const int m0 = 32 * c + 8 * q;
        const float* xp = x + (size_t)b * (NN * 2) + m0 * 2;
        uint4 d;
        unsigned dd[4];
#pragma unroll
        for (int i = 0; i < 4; ++i) {
            float4 xx = *(const float4*)(xp + 4 * i);
            float v0 = ch ? xx.y : xx.x;
            float v1 = ch ? xx.w : xx.z;
            dd[i] = (unsigned)f2b(v0) | ((unsigned)f2b(v1) << 16);
        }
        d.x = dd[0]; d.y = dd[1]; d.z = dd[2]; d.w = dd[3];
        *(uint4*)(VTf + ((size_t)(c * 4 + u) * 64 + lane) * 8) = d;
    } else if (bx < 384) {
        const int cc = t >> 7, tt = t & 127;
        const int c = (bx - 256) * 2 + cc;
        const int h = tt >> 6, lane = tt & 63, l = lane & 15, q = lane >> 4;
        const int row = 32 * c + 8 * (l >> 2) + (l & 3) + 4 * h;
        const float* ap = adj + (size_t)row * EMB + (q & 1) * 8;
        float4 a0 = *(const float4*)(ap);
        float4 a1 = *(const float4*)(ap + 4);
        uint4 d;
        d.x = (unsigned)f2b(a0.x) | ((unsigned)f2b(a0.y) << 16);
        d.y = (unsigned)f2b(a0.z) | ((unsigned)f2b(a0.w) << 16);
        d.z = (unsigned)f2b(a1.x) | ((unsigned)f2b(a1.y) << 16);
        d.w = (unsigned)f2b(a1.z) | ((unsigned)f2b(a1.w) << 16);
        *(uint4*)(Afrag + ((size_t)(c * 2 + h) * 64 + lane) * 8) = d;
    } else {
        const float L2E = 1.4426950408889634f;
        int idx = (bx - 384) * 256 + t;
        float4 aa = *(const float4*)(adj + (size_t)idx * 4);
        uint2 us;
        us.x = (unsigned)f2b(aa.x * L2E) | ((unsigned)f2b(aa.y * L2E) << 16);
        us.y = (unsigned)f2b(aa.z * L2E) | ((unsigned)f2b(aa.w * L2E) << 16);
        *(uint2*)(adjS + (size_t)idx * 4) = us;
    }
}

// ---------------------------------------------------------------------------
// K2a: flash propagation main loop. 256 blocks x 512 thr; block = (tile,mhalf)
// with tile = bx&127 (64 nodes), mhalf = bx>>7 (half the m range). Per-block
// L2 fragment stream halves vs R3 (0.75 MB; aggregate 384->192 MB). 8 waves
// split the 128-cg half-range, 16 cg each; wave covers all 64 n (4 B-frags).
// Wave partials meet in LDS; block partial (fp32) + den written to global.
// ---------------------------------------------------------------------------
__launch_bounds__(512, 1)
__global__ void k_main(const short* __restrict__ Afrag, const short* __restrict__ adjS,
                       const short* __restrict__ VTf,
                       float* __restrict__ gnum, float* __restrict__ gden) {
    const int t = threadIdx.x;
    const int wv = t >> 6;
    const int lane = t & 63;
    const int l = lane & 15;
    const int q = lane >> 4;
    const int tile = blockIdx.x & 127;
    const int mh = blockIdx.x >> 7;
    const int n0 = tile * 64;
    const int cbeg = mh * 128 + wv * 16;
    const int cend = cbeg + 16;

    __shared__ __align__(16) unsigned short ysl[8][64][68];  // bf16 wave partials (69.6 KB)
    __shared__ float dsl[8][64];

    // loop-invariant score B-fragments (log2e-scaled), k>=16 zeroed; 4 x 16 n
    bf16x8 Bn[4];
    bf16x8 zv = {0, 0, 0, 0, 0, 0, 0, 0};
#pragma unroll
    for (int s = 0; s < 4; ++s) {
        const short* src = adjS + (size_t)(n0 + 16 * s + l) * EMB + (q & 1) * 8;
        bf16x8 v = *(const bf16x8*)src;
        Bn[s] = (q < 2) ? v : zv;
    }
    const short one = (short)0x3F80;
    bf16x8 ones = {one, one, one, one, one, one, one, one};

    f32x4 acc[4][4];
    f32x4 dacc[4];
#pragma unroll
    for (int u = 0; u < 4; ++u)
#pragma unroll
        for (int s = 0; s < 4; ++s) { acc[u][s][0] = acc[u][s][1] = acc[u][s][2] = acc[u][s][3] = 0.f; }
#pragma unroll
    for (int s = 0; s < 4; ++s) { dacc[s][0] = dacc[s][1] = dacc[s][2] = dacc[s][3] = 0.f; }

    const short* Ap = Afrag + (size_t)lane * 8;   // + cg*1024 + h*512
    const short* Vp = VTf + (size_t)lane * 8;     // + cg*2048 + u*512

    // prologue: A fragments for first subtile
    bf16x8 aCur0 = *(const bf16x8*)(Ap + (size_t)cbeg * 1024);
    bf16x8 aCur1 = *(const bf16x8*)(Ap + (size_t)cbeg * 1024 + 512);

    for (int cg = cbeg; cg < cend; ++cg) {
        bf16x8 v0 = *(const bf16x8*)(Vp + (size_t)cg * 2048);
        bf16x8 v1 = *(const bf16x8*)(Vp + (size_t)cg * 2048 + 512);
        bf16x8 v2 = *(const bf16x8*)(Vp + (size_t)cg * 2048 + 1024);
        bf16x8 v3 = *(const bf16x8*)(Vp + (size_t)cg * 2048 + 1536);
        const int cgn = (cg + 1 < cend) ? cg + 1 : cbeg;   // clamped redundant last
        bf16x8 aN0 = *(const bf16x8*)(Ap + (size_t)cgn * 1024);
        bf16x8 aN1 = *(const bf16x8*)(Ap + (size_t)cgn * 1024 + 512);

        f32x4 z = {0.f, 0.f, 0.f, 0.f};
        f32x4 S0[4], S1[4];
#pragma unroll
        for (int s = 0; s < 4; ++s) {
            S0[s] = __builtin_amdgcn_mfma_f32_16x16x32_bf16(aCur0, Bn[s], z, 0, 0, 0);
            S1[s] = __builtin_amdgcn_mfma_f32_16x16x32_bf16(aCur1, Bn[s], z, 0, 0, 0);
        }
#pragma unroll
        for (int s = 0; s < 4; ++s) {
            unsigned w0[4], w1[4];
#pragma unroll
            for (int r = 0; r < 4; ++r) {
                union { float f; unsigned u; } p0, p1;
                p0.f = __builtin_amdgcn_exp2f(fmaxf(S0[s][r], 0.f));
                p1.f = __builtin_amdgcn_exp2f(fmaxf(S1[s][r], 0.f));
                w0[r] = p0.u;      // j = r      (h=0)
                w1[r] = p1.u;      // j = 4 + r  (h=1)
            }
            union { bf16x8 v; unsigned d[4]; } pf;
            pf.d[0] = packbf(w0[0], w0[1]);
            pf.d[1] = packbf(w0[2], w0[3]);
            pf.d[2] = packbf(w1[0], w1[1]);
            pf.d[3] = packbf(w1[2], w1[3]);
            acc[0][s] = __builtin_amdgcn_mfma_f32_16x16x32_bf16(v0, pf.v, acc[0][s], 0, 0, 0);
            acc[1][s] = __builtin_amdgcn_mfma_f32_16x16x32_bf16(v1, pf.v, acc[1][s], 0, 0, 0);
            acc[2][s] = __builtin_amdgcn_mfma_f32_16x16x32_bf16(v2, pf.v, acc[2][s], 0, 0, 0);
            acc[3][s] = __builtin_amdgcn_mfma_f32_16x16x32_bf16(v3, pf.v, acc[3][s], 0, 0, 0);
            dacc[s] = __builtin_amdgcn_mfma_f32_16x16x32_bf16(ones, pf.v, dacc[s], 0, 0, 0);
        }
        aCur0 = aN0;
        aCur1 = aN1;
    }

    // dump this wave's partial (bf16 num, f32 den) into its LDS slot
#pragma unroll
    for (int s = 0; s < 4; ++s) {
        const int nl_w = 16 * s + l;
#pragma unroll
        for (int u = 0; u < 4; ++u) {
            union { float f; unsigned u; } a0, a1, a2, a3;
            a0.f = acc[u][s][0]; a1.f = acc[u][s][1]; a2.f = acc[u][s][2]; a3.f = acc[u][s][3];
            uint2 pk;
            pk.x = packbf(a0.u, a1.u);
            pk.y = packbf(a2.u, a3.u);
            *(uint2*)&ysl[wv][nl_w][16 * u + 4 * q] = pk;
        }
        if (q == 0) dsl[wv][nl_w] = dacc[s][0];
    }
    __syncthreads();

    // block combine: fp32 partial [p=mh*128+tile][n(64)][64], den [p][64]
    float* gn = gnum + (size_t)(mh * 128 + tile) * 64 * 64;
    float* gd = gden + (size_t)(mh * 128 + tile) * 64;
    const int nl = t >> 4, og = t & 15;
#pragma unroll
    for (int h = 0; h < 2; ++h) {
        const int nr = nl + 32 * h;
        f32x4 ysum = {0.f, 0.f, 0.f, 0.f};
        float dsum = 0.f;
#pragma unroll
        for (int s = 0; s < 8; ++s) {
            ushort4 p = *(const ushort4*)&ysl[s][nr][og * 4];
            union { unsigned u; float f; } c0, c1, c2, c3;
            c0.u = (unsigned)p.x << 16; c1.u = (unsigned)p.y << 16;
            c2.u = (unsigned)p.z << 16; c3.u = (unsigned)p.w << 16;
            ysum[0] += c0.f; ysum[1] += c1.f; ysum[2] += c2.f; ysum[3] += c3.f;
            dsum += dsl[s][nr];
        }
        *(f32x4*)(gn + (size_t)nr * 64 + og * 4) = ysum;
        if (og == 0) gd[nr] = dsum;
    }
}

// ---------------------------------------------------------------------------
// K2b: epilogue. 256 blocks x 512 thr, 32 nodes each (tile=bx>>1, half=bx&1).
// Combines the two m-half fp32 partials, normalizes, computes node-adaptive
// W in fp32 from adj x wp/bp staged in LDS (replaces bf16 WbufB), writes out.
// ---------------------------------------------------------------------------
__global__ void k_epi2(const float* __restrict__ adj, const float* __restrict__ wp,
                       const float* __restrict__ bp, const float* __restrict__ x,
                       const float* __restrict__ gnum, const float* __restrict__ gden,
                       float* __restrict__ out) {
    const int t = threadIdx.x;
    const int nl = t >> 4, og = t & 15;           // nl in [0,32)
    const int tile = blockIdx.x >> 1;
    const int half = blockIdx.x & 1;
    const int n0 = blockIdx.x * 32;               // global n base (= tile*64 + half*32)
    const int nloc = half * 32 + nl;              // row within tile partial [0,64)
    const int n = n0 + nl;

    __shared__ float wpl[EMB][5][64];   // 20 KB: [d][c][j], c=4 is bias
    __shared__ float adjl[32][EMB];     // 2 KB
    __shared__ float xl[32][68];
    __shared__ float ylf[32][68];

    // stage wp/bp into LDS (fp32)
    for (int i = t; i < EMB * 5 * 64; i += 512) {
        const int d = i / 320, r = i % 320, c = r >> 6, j = r & 63;
        wpl[d][c][j] = (c < 4) ? wp[(size_t)(d * 4 + c) * 64 + j] : bp[(size_t)d * 64 + j];
    }
    // stage adj rows (one float per thread: 32 x 16 = 512)
    adjl[nl][og] = adj[(size_t)(n0 + nl) * EMB + og];

    // combine the two m-half partials, normalize
    const float* gn0 = gnum + (size_t)tile * 64 * 64;
    const float* gn1 = gnum + (size_t)(128 + tile) * 64 * 64;
    f32x4 y0 = *(const f32x4*)(gn0 + (size_t)nloc * 64 + og * 4);
    f32x4 y1 = *(const f32x4*)(gn1 + (size_t)nloc * 64 + og * 4);
    float dsum = gden[(size_t)tile * 64 + nloc] + gden[(size_t)(128 + tile) * 64 + nloc];
    float rden = 1.f / dsum;
    ylf[nl][og * 4 + 0] = (y0[0] + y1[0]) * rden;
    ylf[nl][og * 4 + 1] = (y0[1] + y1[1]) * rden;
    ylf[nl][og * 4 + 2] = (y0[2] + y1[2]) * rden;
    ylf[nl][og * 4 + 3] = (y0[3] + y1[3]) * rden;

    // stage x rows
    float2 x0 = *(const float2*)(x + ((size_t)(og * 2) * NN + n) * 2);
    float2 x1v = *(const float2*)(x + ((size_t)(og * 2 + 1) * NN + n) * 2);
    xl[nl][og * 4 + 0] = x0.x; xl[nl][og * 4 + 1] = x0.y;
    xl[nl][og * 4 + 2] = x1v.x; xl[nl][og * 4 + 3] = x1v.y;
    __syncthreads();

    // node-adaptive weights in fp32: W[c][j4] = sum_d adj[n][d] * wpl[d][c][j4]
    float4 W[5];
#pragma unroll
    for (int c = 0; c < 5; ++c) { W[c].x = W[c].y = W[c].z = W[c].w = 0.f; }
#pragma unroll
    for (int d = 0; d < EMB; ++d) {
        const float a = adjl[nl][d];
#pragma unroll
        for (int c = 0; c < 5; ++c) {
            const float4 p = *(const float4*)&wpl[d][c][og * 4];
            W[c].x += a * p.x; W[c].y += a * p.y; W[c].z += a * p.z; W[c].w += a * p.w;
        }
    }

#pragma unroll 4
    for (int b = 0; b < BB; ++b) {
        float xb0 = xl[nl][2 * b], xb1 = xl[nl][2 * b + 1];
        float yb0 = ylf[nl][2 * b], yb1 = ylf[nl][2 * b + 1];
        f32x4 o4;
        o4[0] = xb0 * W[0].x + xb1 * W[1].x + yb0 * W[2].x + yb1 * W[3].x + W[4].x;
        o4[1] = xb0 * W[0].y + xb1 * W[1].y + yb0 * W[2].y + yb1 * W[3].y + W[4].y;
        o4[2] = xb0 * W[0].z + xb1 * W[1].z + yb0 * W[2].z + yb1 * W[3].z + W[4].z;
        o4[3] = xb0 * W[0].w + xb1 * W[1].w + yb0 * W[2].w + yb1 * W[3].w + W[4].w;
        __builtin_nontemporal_store(o4, (f32x4*)(out + ((size_t)b * NN + n) * HID + og * 4));
    }
}

// ---------------------------------------------------------------------------
extern "C" void kernel_launch(void* const* d_in, const int* in_sizes, int n_in,
                              void* d_out, int out_size, void* d_ws, size_t ws_size,
                              hipStream_t stream) {
    const float* x   = (const float*)d_in[0];   // [32, 8192, 2]
    const float* adj = (const float*)d_in[1];   // [8192, 16]
    const float* wp  = (const float*)d_in[2];   // [16, 2, 2, 64]
    const float* bp  = (const float*)d_in[3];   // [16, 64]
    float* out = (float*)d_out;                 // [32, 8192, 64]

    char* w = (char*)d_ws;
    short* VTf   = (short*)w;                                   // 1 MB
    short* Afrag = VTf + (size_t)256 * 4 * 64 * 8;              // 512 KB
    short* adjS  = Afrag + (size_t)256 * 2 * 64 * 8;            // 256 KB
    float* gnum  = (float*)(adjS + (size_t)NN * EMB);           // 4 MB  [256][64][64]
    float* gden  = gnum + (size_t)256 * 64 * 64;                // 64 KB [256][64]

    k_build<<<512, 256, 0, stream>>>(x, adj, VTf, Afrag, adjS);
    k_main<<<256, 512, 0, stream>>>(Afrag, adjS, VTf, gnum, gden);
    k_epi2<<<256, 512, 0, stream>>>(adj, wp, bp, x, gnum, gden, out);
}